// Round 11
// baseline (37.648 us; speedup 1.0000x reference)
//
#include <hip/hip_runtime.h>
#include <hip/hip_bf16.h>
#include <math.h>

#define NUM_GRAPHS 512
#define D 128
#define CAP 136      // staged rows per (segment,modality); 2*CAP*256B + ~9.3KB static -> 2 blocks/CU
#define ROWB 256     // bytes per staged bf16 row (128 * 2B)

__device__ inline int lower_bound_i(const int* __restrict__ b, int n, int v) {
    int lo = 0, hi = n;
    while (lo < hi) {
        int mid = (lo + hi) >> 1;
        if (b[mid] < v) lo = mid + 1; else hi = mid;
    }
    return lo;
}

__device__ inline void add4(float4& a, const float4 v) {
    a.x += v.x; a.y += v.y; a.z += v.z; a.w += v.w;
}

// Stage one float4 (fp32 dims 4c..4c+3 of row idx) as 8B of bf16 into LDS.
// v_cvt_pk_bf16_f32 via __float22bfloat162_rn (2 instr vs 18 manual bitops).
// Chunk-XOR swizzle (16B chunks, ^ (idx&7)) keeps phase-C ds_read conflicts low.
__device__ inline void stage(unsigned char* zb, int idx, int c, float4 v) {
    if (idx >= CAP) return;
    __hip_bfloat162 h01 = __float22bfloat162_rn(make_float2(v.x, v.y));
    __hip_bfloat162 h23 = __float22bfloat162_rn(make_float2(v.z, v.w));
    const unsigned int lo = *reinterpret_cast<unsigned int*>(&h01);
    const unsigned int hi = *reinterpret_cast<unsigned int*>(&h23);
    const int chunk = (c >> 1) ^ (idx & 7);
    *reinterpret_cast<uint2*>(zb + (size_t)idx * ROWB + chunk * 16 + (c & 1) * 8)
        = make_uint2(lo, hi);
}

// One block per segment s, 512 threads; half (t>>8) = modality.
// Phase A: single HBM pass, SOFTWARE-PIPELINED (R10 lesson: non-pipelined quad
//          drains vmcnt to 0 each iter -> ~2 loads in flight -> 3.2 TB/s).
//          Ping-pong v/u register quads keep 4-8 loads in flight.
//          fp32 segment-sum (exact) + bf16 LDS copy of first CAP rows.
// Phase B: normalize g. Phase C: quad-per-row dots + JSD (staged rows from
//          LDS; overflow rows from global = L3-resident).
__global__ __launch_bounds__(512, 4) void fused_gcl(
    const float* __restrict__ z1, const float* __restrict__ z2,
    const int* __restrict__ b1, const int* __restrict__ b2,
    float* __restrict__ dsq, int N)
{
    extern __shared__ unsigned char smem[];    // 2 * CAP * ROWB bytes
    const int s    = blockIdx.x;
    const int t    = threadIdx.x;
    const int half = t >> 8;     // 0: z1/b1, 1: z2/b2
    const int tt   = t & 255;

    const float* z = half ? z2 : z1;
    const int*   b = half ? b2 : b1;
    unsigned char* zb = smem + (size_t)half * CAP * ROWB;

    __shared__ int    bnds[2][2];
    __shared__ float4 part[2][8][32];
    __shared__ float  gbuf[2][D];
    __shared__ float  warr[2][4];

    if (tt < 2) bnds[half][tt] = lower_bound_i(b, N, s + tt);
    __syncthreads();
    const int start = bnds[half][0], end = bnds[half][1];
    const int cnt    = end - start;
    const int staged = cnt < CAP ? cnt : CAP;

    // ---- Phase A: pipelined single pass: fp32 sum + bf16 stage ----
    {
        const int r = tt >> 5;   // 0..7
        const int c = tt & 31;   // float4 col
        const float4* Z = reinterpret_cast<const float4*>(z);
        float4 a0 = make_float4(0.f, 0.f, 0.f, 0.f), a1 = a0, a2 = a0, a3 = a0;
        int row = start + r;
        if (row + 24 < end) {
            float4 v0 = Z[(size_t)row * 32 + c];
            float4 v1 = Z[(size_t)(row + 8)  * 32 + c];
            float4 v2 = Z[(size_t)(row + 16) * 32 + c];
            float4 v3 = Z[(size_t)(row + 24) * 32 + c];
            int prow = row;
            row += 32;
            for (; row + 24 < end; row += 32) {
                // issue next quad BEFORE consuming current -> loads stay in flight
                float4 u0 = Z[(size_t)row * 32 + c];
                float4 u1 = Z[(size_t)(row + 8)  * 32 + c];
                float4 u2 = Z[(size_t)(row + 16) * 32 + c];
                float4 u3 = Z[(size_t)(row + 24) * 32 + c];
                add4(a0, v0); stage(zb, prow - start,      c, v0);
                add4(a1, v1); stage(zb, prow - start + 8,  c, v1);
                add4(a2, v2); stage(zb, prow - start + 16, c, v2);
                add4(a3, v3); stage(zb, prow - start + 24, c, v3);
                v0 = u0; v1 = u1; v2 = u2; v3 = u3;
                prow = row;
            }
            add4(a0, v0); stage(zb, prow - start,      c, v0);
            add4(a1, v1); stage(zb, prow - start + 8,  c, v1);
            add4(a2, v2); stage(zb, prow - start + 16, c, v2);
            add4(a3, v3); stage(zb, prow - start + 24, c, v3);
        }
        for (; row < end; row += 8) {
            float4 v = Z[(size_t)row * 32 + c];
            add4(a0, v);
            stage(zb, row - start, c, v);
        }
        add4(a0, a1); add4(a2, a3); add4(a0, a2);
        part[half][r][c] = a0;
    }
    __syncthreads();

    // ---- Phase B: reduce + normalize g into gbuf[half] ----
    if (tt < 32) {
        float4 sum = part[half][0][tt];
#pragma unroll
        for (int g = 1; g < 8; ++g) add4(sum, part[half][g][tt]);
        float ss = sum.x * sum.x + sum.y * sum.y + sum.z * sum.z + sum.w * sum.w;
#pragma unroll
        for (int m = 1; m <= 16; m <<= 1) ss += __shfl_xor(ss, m, 64);
        const float inv = 1.0f / fmaxf(sqrtf(ss), 1e-12f);
        sum.x *= inv; sum.y *= inv; sum.z *= inv; sum.w *= inv;
        reinterpret_cast<float4*>(gbuf[half])[tt] = sum;
    }
    __syncthreads();

    // ---- Phase C: quad-per-row dots + JSD ----
    const int q   = tt & 3;    // quarter of row: dims 32q..32q+31
    const int rid = tt >> 2;   // 0..63
    float4 gpv[8], gcv[8];
    {
        const float4* GP = reinterpret_cast<const float4*>(gbuf[half])     + q * 8;
        const float4* GC = reinterpret_cast<const float4*>(gbuf[half ^ 1]) + q * 8;
#pragma unroll
        for (int i = 0; i < 8; ++i) { gpv[i] = GP[i]; gcv[i] = GC[i]; }
    }

    float acc = 0.f;
    // staged rows: bf16 from LDS
    for (int idx = rid; idx < staged; idx += 64) {
        const unsigned char* rowp = zb + (size_t)idx * ROWB;
        const int x = idx & 7;
        float p = 0.f, cr = 0.f, ssv = 0.f;
#pragma unroll
        for (int j = 0; j < 4; ++j) {
            const int chunk = (q * 4 + j) ^ x;
            const uint4 u = *reinterpret_cast<const uint4*>(rowp + chunk * 16);
            const float4 gp = gpv[2 * j], gq = gpv[2 * j + 1];
            const float4 hp = gcv[2 * j], hq = gcv[2 * j + 1];
            const float f0 = __uint_as_float(u.x << 16);
            const float f1 = __uint_as_float(u.x & 0xffff0000u);
            const float f2 = __uint_as_float(u.y << 16);
            const float f3 = __uint_as_float(u.y & 0xffff0000u);
            const float f4 = __uint_as_float(u.z << 16);
            const float f5 = __uint_as_float(u.z & 0xffff0000u);
            const float f6 = __uint_as_float(u.w << 16);
            const float f7 = __uint_as_float(u.w & 0xffff0000u);
            p   += f0*gp.x + f1*gp.y + f2*gp.z + f3*gp.w
                 + f4*gq.x + f5*gq.y + f6*gq.z + f7*gq.w;
            cr  += f0*hp.x + f1*hp.y + f2*hp.z + f3*hp.w
                 + f4*hq.x + f5*hq.y + f6*hq.z + f7*hq.w;
            ssv += f0*f0 + f1*f1 + f2*f2 + f3*f3 + f4*f4 + f5*f5 + f6*f6 + f7*f7;
        }
        p   += __shfl_xor(p, 1, 64);   p   += __shfl_xor(p, 2, 64);
        cr  += __shfl_xor(cr, 1, 64);  cr  += __shfl_xor(cr, 2, 64);
        ssv += __shfl_xor(ssv, 1, 64); ssv += __shfl_xor(ssv, 2, 64);
        if (q == 0) {
            const float invz  = 1.0f / fmaxf(sqrtf(ssv), 1e-12f);
            const float pos   = p  * invz;
            const float cross = cr * invz;
            const float d = log1pf(__expf(-cross)) - log1pf(__expf(-pos));
            acc += d * d;
        }
    }
    // un-staged rows: exact fp32 from global (L3-resident — just streamed in A)
    for (int idx = staged + rid; idx < cnt; idx += 64) {
        const int row = start + idx;
        const float4* Z = reinterpret_cast<const float4*>(z);
        float p = 0.f, cr = 0.f, ssv = 0.f;
#pragma unroll
        for (int i = 0; i < 8; ++i) {
            float4 zv = Z[(size_t)row * 32 + q * 8 + i];
            p   += zv.x * gpv[i].x + zv.y * gpv[i].y + zv.z * gpv[i].z + zv.w * gpv[i].w;
            cr  += zv.x * gcv[i].x + zv.y * gcv[i].y + zv.z * gcv[i].z + zv.w * gcv[i].w;
            ssv += zv.x * zv.x + zv.y * zv.y + zv.z * zv.z + zv.w * zv.w;
        }
        p   += __shfl_xor(p, 1, 64);   p   += __shfl_xor(p, 2, 64);
        cr  += __shfl_xor(cr, 1, 64);  cr  += __shfl_xor(cr, 2, 64);
        ssv += __shfl_xor(ssv, 1, 64); ssv += __shfl_xor(ssv, 2, 64);
        if (q == 0) {
            const float invz  = 1.0f / fmaxf(sqrtf(ssv), 1e-12f);
            const float pos   = p  * invz;
            const float cross = cr * invz;
            const float d = log1pf(__expf(-cross)) - log1pf(__expf(-pos));
            acc += d * d;
        }
    }

#pragma unroll
    for (int m = 1; m <= 32; m <<= 1) acc += __shfl_xor(acc, m, 64);
    if ((tt & 63) == 0) warr[half][tt >> 6] = acc;
    __syncthreads();
    if (tt == 0)
        dsq[half * NUM_GRAPHS + s] = warr[half][0] + warr[half][1]
                                   + warr[half][2] + warr[half][3];
}

// Single block, 1024 threads: dsq[0..511] -> s0, dsq[512..1023] -> s1.
__global__ __launch_bounds__(1024) void finalize_kernel(const float* __restrict__ dsq,
                                                        float* __restrict__ out) {
    const int t = threadIdx.x;
    float v = dsq[t];
#pragma unroll
    for (int m = 1; m <= 32; m <<= 1) v += __shfl_xor(v, m, 64);
    __shared__ float w[16];
    if ((t & 63) == 0) w[t >> 6] = v;
    __syncthreads();
    if (t == 0) {
        float s0 = 0.f, s1 = 0.f;
#pragma unroll
        for (int i = 0; i < 8; ++i)  s0 += w[i];
#pragma unroll
        for (int i = 8; i < 16; ++i) s1 += w[i];
        out[0] = sqrtf(s0) + sqrtf(s1);
    }
}

extern "C" void kernel_launch(void* const* d_in, const int* in_sizes, int n_in,
                              void* d_out, int out_size, void* d_ws, size_t ws_size,
                              hipStream_t stream) {
    const float* z1 = (const float*)d_in[0];
    const float* z2 = (const float*)d_in[1];
    const int*   b1 = (const int*)d_in[2];
    const int*   b2 = (const int*)d_in[3];
    const int N = in_sizes[2];

    float* dsq = (float*)d_ws;   // 1024 floats, fully written every call

    const int smem_bytes = 2 * CAP * ROWB;   // 69632 B dynamic (+ ~9.3 KB static)
    (void)hipFuncSetAttribute((const void*)fused_gcl,
                              hipFuncAttributeMaxDynamicSharedMemorySize, smem_bytes);

    fused_gcl<<<NUM_GRAPHS, 512, smem_bytes, stream>>>(z1, z2, b1, b2, dsq, N);
    finalize_kernel<<<1, 1024, 0, stream>>>(dsq, (float*)d_out);
}